// Round 6
// baseline (102.532 us; speedup 1.0000x reference)
//
#include <hip/hip_runtime.h>

// Problem constants
#define BATCH 16384
#define ZDIM  256
#define NCLS  1000
#define NPAD  1024

typedef __bf16 bf16x8 __attribute__((ext_vector_type(8)));
typedef float  f32x4  __attribute__((ext_vector_type(4)));

// Workspace layout (bytes). xb/cb are stored PRE-SWIZZLED in MFMA fragment
// order: chunk((tile,kt,lane)) = ((tile*8 + kt)*64 + lane) * 16B, where the
// chunk holds src[tile*16 + (lane&15)][kt*32 + (lane>>4)*8 .. +8] as bf16.
// A fragment load in the GEMM is then one lane-linear global_load_dwordx4.
//   xb   : bf16[16384*256] swizzled  @ 0         (8,388,608 B)
//   cb   : bf16[1024*256]  swizzled  @ 8388608   (524,288 B)
//   xsq  : float[BATCH]              @ 8912896
//   csq  : float[NPAD]               @ 8978432
//   part : float[1024]               @ 8982528   (per-block partial sums)
#define WS_XB   0
#define WS_CB   8388608
#define WS_XSQ  8912896
#define WS_CSQ  8978432
#define WS_PART 8982528

__device__ __forceinline__ unsigned short f2bf(float f) {
    union { float f; unsigned int u; } v; v.f = f;
    unsigned int u = v.u;
    unsigned int r = (u + 0x7fffu + ((u >> 16) & 1u)) >> 16;   // RNE
    return (unsigned short)r;
}

// Fused prep. Blocks [0,256): x -> swizzled xb + xsq (wave per 16-row tile).
// Blocks [256,272): centers -> swizzled cb (zero-padded to 1024) + csq.
__global__ void prep(const float* __restrict__ x,
                     const float* __restrict__ centers,
                     unsigned short* __restrict__ xb,
                     unsigned short* __restrict__ cb,
                     float* __restrict__ xsq,
                     float* __restrict__ csq) {
    const int wid  = threadIdx.x >> 6;
    const int lane = threadIdx.x & 63;
    const int lr   = lane & 15;
    const int quad = lane >> 4;

    if (blockIdx.x < 256) {
        const int mt = blockIdx.x * 4 + wid;                 // 0..1023
        const float* src = x + (size_t)(mt * 16 + lr) * ZDIM + quad * 8;
        float s = 0.0f;
        #pragma unroll
        for (int kt = 0; kt < 8; ++kt) {
            const float4 a = *(const float4*)(src + kt * 32);
            const float4 b = *(const float4*)(src + kt * 32 + 4);
            s += a.x*a.x + a.y*a.y + a.z*a.z + a.w*a.w
               + b.x*b.x + b.y*b.y + b.z*b.z + b.w*b.w;
            unsigned short* dst = xb + ((size_t)(mt * 8 + kt) * 64 + lane) * 8;
            ushort4 lo, hi;
            lo.x = f2bf(a.x); lo.y = f2bf(a.y); lo.z = f2bf(a.z); lo.w = f2bf(a.w);
            hi.x = f2bf(b.x); hi.y = f2bf(b.y); hi.z = f2bf(b.z); hi.w = f2bf(b.w);
            *(ushort4*)dst       = lo;
            *(ushort4*)(dst + 4) = hi;
        }
        s += __shfl_xor(s, 16);
        s += __shfl_xor(s, 32);
        if (lane < 16) xsq[mt * 16 + lane] = s;
    } else {
        const int ct  = (blockIdx.x - 256) * 4 + wid;        // 0..63
        const int row = ct * 16 + lr;
        const bool ok = (row < NCLS);
        const float* src = centers + (size_t)row * ZDIM + quad * 8;
        float s = 0.0f;
        #pragma unroll
        for (int kt = 0; kt < 8; ++kt) {
            float4 a = {0,0,0,0}, b = {0,0,0,0};
            if (ok) {
                a = *(const float4*)(src + kt * 32);
                b = *(const float4*)(src + kt * 32 + 4);
            }
            s += a.x*a.x + a.y*a.y + a.z*a.z + a.w*a.w
               + b.x*b.x + b.y*b.y + b.z*b.z + b.w*b.w;
            unsigned short* dst = cb + ((size_t)(ct * 8 + kt) * 64 + lane) * 8;
            ushort4 lo, hi;
            lo.x = f2bf(a.x); lo.y = f2bf(a.y); lo.z = f2bf(a.z); lo.w = f2bf(a.w);
            hi.x = f2bf(b.x); hi.y = f2bf(b.y); hi.z = f2bf(b.z); hi.w = f2bf(b.w);
            *(ushort4*)dst       = lo;
            *(ushort4*)(dst + 4) = hi;
        }
        s += __shfl_xor(s, 16);
        s += __shfl_xor(s, 32);
        if (lane < 16) csq[ct * 16 + lane] = s;   // pad rows accumulated zeros
    }
}

#define LOAD_PANEL(abuf, bbuf, KT)                                            \
    do {                                                                      \
        _Pragma("unroll")                                                     \
        for (int i = 0; i < 4; ++i)                                           \
            abuf[i] = A[((size_t)(mtb + i) * 8 + (KT)) * 64 + lane];          \
        _Pragma("unroll")                                                     \
        for (int j = 0; j < 4; ++j)                                           \
            bbuf[j] = B[((size_t)(ctb + j) * 8 + (KT)) * 64 + lane];          \
    } while (0)

#define MFMA_PANEL(abuf, bbuf)                                                \
    do {                                                                      \
        _Pragma("unroll")                                                     \
        for (int i = 0; i < 4; ++i)                                           \
            _Pragma("unroll")                                                 \
            for (int j = 0; j < 4; ++j)                                       \
                acc_r[i][j] = __builtin_amdgcn_mfma_f32_16x16x32_bf16(        \
                    abuf[i], bbuf[j], acc_r[i][j], 0, 0, 0);                  \
    } while (0)

// Fused GEMM + distance + mask + block reduce.
// XCD-aware mapping (round 5): bm = blockIdx%128 -> all 8 blocks sharing an
// A-tile land on the same XCD (round-robin %8 dispatch), FETCH 33.8->~12MB.
// Round-6 change: REGISTER DOUBLE-BUFFERED kt-loop. Round 3-5 evidence:
// warm-cache replays (FETCH~65KB) still ran 51us -> not BW-bound; VGPR=68
// showed the compiler reused one frag set, draining vmcnt every panel.
// Prefetch panel kt+1 into a second register set while panel kt's 16 MFMAs
// issue. 64 acc(AGPR) + 64 frag(VGPR) + addr ~ 150 regs, fits 3 waves/EU.
__global__ __launch_bounds__(256, 3) void gemm_loss(
        const unsigned short* __restrict__ xb,
        const unsigned short* __restrict__ cb,
        const float* __restrict__ xsq,
        const float* __restrict__ csq,
        const int* __restrict__ labels,
        float* __restrict__ part) {
    __shared__ float xsq_s[128];
    __shared__ float csq_s[128];
    __shared__ int   lab_s[128];
    __shared__ float wsum[4];

    const int tid  = threadIdx.x;
    const int lane = tid & 63;
    const int wid  = tid >> 6;
    const int bm   = blockIdx.x & 127;     // 0..127  (same bm -> same XCD)
    const int bn   = blockIdx.x >> 7;      // 0..7
    const int m0   = bm * 128;
    const int n0   = bn * 128;

    if (tid < 128) {
        xsq_s[tid] = xsq[m0 + tid];
        lab_s[tid] = labels[m0 + tid];
    } else {
        const int t = tid - 128;
        csq_s[t] = csq[n0 + t];
    }

    const int wm = wid & 1;      // wave row (0/1) -> 64 rows
    const int wn = wid >> 1;     // wave col (0/1) -> 64 cols

    f32x4 acc_r[4][4];
    #pragma unroll
    for (int i = 0; i < 4; ++i)
        #pragma unroll
        for (int j = 0; j < 4; ++j) {
            f32x4 z = {0.0f, 0.0f, 0.0f, 0.0f};
            acc_r[i][j] = z;
        }

    const int mtb = bm * 8 + wm * 4;       // first of 4 A 16-row tiles
    const int ctb = bn * 8 + wn * 4;       // first of 4 B 16-col tiles
    const bf16x8* __restrict__ A = (const bf16x8*)xb;
    const bf16x8* __restrict__ B = (const bf16x8*)cb;

    bf16x8 a0[4], b0[4], a1[4], b1[4];
    LOAD_PANEL(a0, b0, 0);
    #pragma unroll
    for (int kt = 0; kt < 8; kt += 2) {
        if (kt + 1 < 8) LOAD_PANEL(a1, b1, kt + 1);   // prefetch while a0/b0 compute
        MFMA_PANEL(a0, b0);
        if (kt + 2 < 8) LOAD_PANEL(a0, b0, kt + 2);   // prefetch while a1/b1 compute
        MFMA_PANEL(a1, b1);
    }

    __syncthreads();   // staging of xsq_s/csq_s/lab_s visible before epilogue

    // Epilogue: dist -> sqrt -> clamp -> mask (label & pad) -> sum
    // C/D layout (16x16): col = lane&15, row = (lane>>4)*4 + reg  [m89/m91]
    const int quad = lane >> 4;
    const int lr   = lane & 15;
    float sum = 0.0f;
    #pragma unroll
    for (int j = 0; j < 4; ++j) {
        const int col_l = wn * 64 + j * 16 + lr;
        const int col_g = n0 + col_l;
        const float cs = csq_s[col_l];
        const bool colok = (col_g < NCLS);
        #pragma unroll
        for (int i = 0; i < 4; ++i) {
            #pragma unroll
            for (int r = 0; r < 4; ++r) {
                const int row_l = wm * 64 + i * 16 + quad * 4 + r;
                float dist = xsq_s[row_l] + cs - 2.0f * acc_r[i][j][r];
                float d = sqrtf(fmaxf(dist, 0.0f));
                d = fminf(fmaxf(d, 1e-8f), 1e8f);
                if (colok && (lab_s[row_l] != col_g)) sum += d;
            }
        }
    }

    #pragma unroll
    for (int off = 32; off; off >>= 1) sum += __shfl_down(sum, off);
    if (lane == 0) wsum[wid] = sum;
    __syncthreads();
    if (tid == 0) part[blockIdx.x] = wsum[0] + wsum[1] + wsum[2] + wsum[3];
}

// Reduce 1024 partials -> loss. One block; no atomics anywhere.
__global__ void finalize(const float* __restrict__ part, float* __restrict__ out) {
    const int tid  = threadIdx.x;
    const int lane = tid & 63;
    const int wid  = tid >> 6;
    __shared__ float wsum[4];
    float s = part[tid] + part[tid + 256] + part[tid + 512] + part[tid + 768];
    #pragma unroll
    for (int off = 32; off; off >>= 1) s += __shfl_down(s, off);
    if (lane == 0) wsum[wid] = s;
    __syncthreads();
    if (tid == 0)
        out[0] = (wsum[0] + wsum[1] + wsum[2] + wsum[3]) * (1.0f / (16384.0f * 999.0f));
}

extern "C" void kernel_launch(void* const* d_in, const int* in_sizes, int n_in,
                              void* d_out, int out_size, void* d_ws, size_t ws_size,
                              hipStream_t stream) {
    const float* x       = (const float*)d_in[0];
    const float* centers = (const float*)d_in[1];
    const int*   labels  = (const int*)d_in[2];
    float*       out     = (float*)d_out;

    char* ws = (char*)d_ws;
    unsigned short* xb   = (unsigned short*)(ws + WS_XB);
    unsigned short* cb   = (unsigned short*)(ws + WS_CB);
    float*          xsq  = (float*)(ws + WS_XSQ);
    float*          csq  = (float*)(ws + WS_CSQ);
    float*          part = (float*)(ws + WS_PART);

    prep<<<272, 256, 0, stream>>>(x, centers, xb, cb, xsq, csq);
    gemm_loss<<<(BATCH / 128) * (NPAD / 128), 256, 0, stream>>>(
        xb, cb, xsq, csq, labels, part);
    finalize<<<1, 256, 0, stream>>>(part, out);
}

// Round 8
// 94.569 us; speedup vs baseline: 1.0842x; 1.0842x over previous
//
#include <hip/hip_runtime.h>

// Problem constants
#define BATCH 16384
#define ZDIM  256
#define NCLS  1000
#define NPAD  1024

typedef float f32x4 __attribute__((ext_vector_type(4)));

// Workspace layout (bytes). xq/cq are fp8 e4m3, PRE-SWIZZLED in MFMA fragment
// order: byte((tile,kt,lane,j)) = ((tile*8 + kt)*64 + lane)*8 + j, holding
// src[tile*16 + (lane&15)][kt*32 + (lane>>4)*8 + j]. (Same index math as the
// verified bf16 16x16x32 layout; elements are bytes. C/D layout is
// dtype-independent [m121-m128].)
//   xq   : fp8[16384*256]  @ 0         (4,194,304 B)
//   cq   : fp8[1024*256]   @ 4194304   (262,144 B)
//   xsq  : float[BATCH]    @ 4456448   (65,536 B)
//   csq  : float[NPAD]     @ 4521984   (4,096 B)
//   part : float[256]      @ 4526080   (1,024 B)
#define WS_XQ   0
#define WS_CQ   4194304
#define WS_XSQ  4456448
#define WS_CSQ  4521984
#define WS_PART 4526080

#define GLOAD_LDS(gp, lp)                                                     \
    __builtin_amdgcn_global_load_lds(                                         \
        (__attribute__((address_space(1))) const void*)(gp),                  \
        (__attribute__((address_space(3))) void*)(lp), 16, 0, 0)

// word-select must be an immediate -> template parameter (round-7 fix)
template <bool W>
__device__ __forceinline__ int pk2fp8(float a, float b, int old) {
    return __builtin_amdgcn_cvt_pk_fp8_f32(a, b, old, W);
}

// Fused prep: fp32 -> fp8 e4m3 fragment-ordered + row norms (fp32, exact).
// Blocks [0,256): x (wave per 16-row tile). Blocks [256,272): centers padded.
__global__ void prep(const float* __restrict__ x,
                     const float* __restrict__ centers,
                     char* __restrict__ xq,
                     char* __restrict__ cq,
                     float* __restrict__ xsq,
                     float* __restrict__ csq) {
    const int wid  = threadIdx.x >> 6;
    const int lane = threadIdx.x & 63;
    const int lr   = lane & 15;
    const int quad = lane >> 4;

    if (blockIdx.x < 256) {
        const int mt = blockIdx.x * 4 + wid;                 // 0..1023
        const float* src = x + (size_t)(mt * 16 + lr) * ZDIM + quad * 8;
        float s = 0.0f;
        #pragma unroll
        for (int kt = 0; kt < 8; ++kt) {
            const float4 a = *(const float4*)(src + kt * 32);
            const float4 b = *(const float4*)(src + kt * 32 + 4);
            s += a.x*a.x + a.y*a.y + a.z*a.z + a.w*a.w
               + b.x*b.x + b.y*b.y + b.z*b.z + b.w*b.w;
            int lo = pk2fp8<false>(a.x, a.y, 0); lo = pk2fp8<true>(a.z, a.w, lo);
            int hi = pk2fp8<false>(b.x, b.y, 0); hi = pk2fp8<true>(b.z, b.w, hi);
            int2 v; v.x = lo; v.y = hi;
            *(int2*)(xq + ((size_t)(mt * 8 + kt) * 64 + lane) * 8) = v;
        }
        s += __shfl_xor(s, 16);
        s += __shfl_xor(s, 32);
        if (lane < 16) xsq[mt * 16 + lane] = s;
    } else {
        const int ct  = (blockIdx.x - 256) * 4 + wid;        // 0..63
        const int row = ct * 16 + lr;
        const bool ok = (row < NCLS);
        const float* src = centers + (size_t)row * ZDIM + quad * 8;
        float s = 0.0f;
        #pragma unroll
        for (int kt = 0; kt < 8; ++kt) {
            float4 a = {0,0,0,0}, b = {0,0,0,0};
            if (ok) {
                a = *(const float4*)(src + kt * 32);
                b = *(const float4*)(src + kt * 32 + 4);
            }
            s += a.x*a.x + a.y*a.y + a.z*a.z + a.w*a.w
               + b.x*b.x + b.y*b.y + b.z*b.z + b.w*b.w;
            int lo = pk2fp8<false>(a.x, a.y, 0); lo = pk2fp8<true>(a.z, a.w, lo);
            int hi = pk2fp8<false>(b.x, b.y, 0); hi = pk2fp8<true>(b.z, b.w, hi);
            int2 v; v.x = lo; v.y = hi;
            *(int2*)(cq + ((size_t)(ct * 8 + kt) * 64 + lane) * 8) = v;
        }
        s += __shfl_xor(s, 16);
        s += __shfl_xor(s, 32);
        if (lane < 16) csq[ct * 16 + lane] = s;   // pad rows got zeros
    }
}

// Fused fp8 GEMM + distance + mask + block reduce.
// 256x256 tile/block, 512 threads (8 waves, 4 row-groups x 2 col-groups).
// Grid 256 = 1 block/CU. Vmem traffic = 128 KB/CU (A-tile 64K + B-tile 64K
// staged to LDS once, in two K=128 halves through one 64 KB buffer).
// Rounds 2-6 lesson: the binding resource is the per-CU vmem port
// (~9 B/cyc); register-direct designs moved 268 MB -> 53 us wall. This
// moves 33.5 MB total.
// XCD: bm = blockIdx&63; sharers {bm,bm+64,bm+128,bm+192} === bm (mod 8)
// -> same XCD for A-tile reuse in L2.
__global__ __launch_bounds__(512, 2) void gemm_loss(
        const char* __restrict__ xq,
        const char* __restrict__ cq,
        const float* __restrict__ xsq,
        const float* __restrict__ csq,
        const int* __restrict__ labels,
        float* __restrict__ part) {
    __shared__ char smem[65536];   // A half: [0,32K) = [mtile16][kt4][512B]; B half: [32K,64K)

    const int tid  = threadIdx.x;
    const int lane = tid & 63;
    const int wid  = tid >> 6;
    const int bm   = blockIdx.x & 63;      // 0..63
    const int bn   = blockIdx.x >> 6;      // 0..3
    const int m0   = bm * 256;
    const int n0   = bn * 256;
    const int wr   = wid & 3;              // wave row group: 64 rows
    const int wc   = wid >> 2;             // wave col group: 128 cols

    f32x4 acc_r[4][8];
    #pragma unroll
    for (int i = 0; i < 4; ++i)
        #pragma unroll
        for (int j = 0; j < 8; ++j) {
            f32x4 z = {0.0f, 0.0f, 0.0f, 0.0f};
            acc_r[i][j] = z;
        }

    const long long* AL = (const long long*)smem;
    const long long* BL = (const long long*)(smem + 32768);

    #pragma unroll
    for (int h = 0; h < 2; ++h) {
        // Stage A half: 16 mtiles x 4 kt x 512 B = 32 KB (4 iters x 8 KB)
        #pragma unroll
        for (int it = 0; it < 4; ++it) {
            const int c = it * 512 + tid;              // 0..2047 (16B chunks)
            const int mtile = c >> 7, kt4 = (c >> 5) & 3, pair = c & 31;
            const char* g = xq + (size_t)((bm * 16 + mtile) * 8 + h * 4 + kt4) * 512
                               + pair * 16;
            GLOAD_LDS(g, smem + c * 16);
        }
        // Stage B half: 16 ctiles x 4 kt x 512 B = 32 KB
        #pragma unroll
        for (int it = 0; it < 4; ++it) {
            const int c = it * 512 + tid;
            const int ctile = c >> 7, kt4 = (c >> 5) & 3, pair = c & 31;
            const char* g = cq + (size_t)((bn * 16 + ctile) * 8 + h * 4 + kt4) * 512
                               + pair * 16;
            GLOAD_LDS(g, smem + 32768 + c * 16);
        }
        __syncthreads();

        #pragma unroll
        for (int kt4 = 0; kt4 < 4; ++kt4) {
            long long af[4], bf[8];
            #pragma unroll
            for (int mi = 0; mi < 4; ++mi)
                af[mi] = AL[((wr * 4 + mi) * 4 + kt4) * 64 + lane];
            #pragma unroll
            for (int nj = 0; nj < 8; ++nj)
                bf[nj] = BL[((wc * 8 + nj) * 4 + kt4) * 64 + lane];
            #pragma unroll
            for (int mi = 0; mi < 4; ++mi)
                #pragma unroll
                for (int nj = 0; nj < 8; ++nj)
                    acc_r[mi][nj] = __builtin_amdgcn_mfma_f32_16x16x32_fp8_fp8(
                        af[mi], bf[nj], acc_r[mi][nj], 0, 0, 0);
        }
        __syncthreads();   // protect LDS before next-half overwrite / extras
    }

    // Reuse dead LDS for epilogue scalars
    float* xsq_s = (float*)smem;             // 256 f32
    float* csq_s = (float*)(smem + 1024);    // 256 f32
    int*   lab_s = (int*)(smem + 2048);      // 256 i32
    float* wsum  = (float*)(smem + 3072);    // 8 f32
    if (tid < 256) {
        xsq_s[tid] = xsq[m0 + tid];
        lab_s[tid] = labels[m0 + tid];
    } else {
        const int t = tid - 256;
        csq_s[t] = csq[n0 + t];
    }
    __syncthreads();

    // Epilogue: dist -> sqrt -> clamp -> mask (label & pad) -> sum
    // C/D layout (16x16): col = lane&15, row = (lane>>4)*4 + reg  [m89/m91]
    const int quad = lane >> 4;
    const int lr   = lane & 15;
    float sum = 0.0f;
    #pragma unroll
    for (int nj = 0; nj < 8; ++nj) {
        const int col_l = wc * 128 + nj * 16 + lr;
        const int col_g = n0 + col_l;
        const float cs = csq_s[col_l];
        const bool colok = (col_g < NCLS);
        #pragma unroll
        for (int mi = 0; mi < 4; ++mi) {
            #pragma unroll
            for (int r = 0; r < 4; ++r) {
                const int row_l = wr * 64 + mi * 16 + quad * 4 + r;
                float dist = xsq_s[row_l] + cs - 2.0f * acc_r[mi][nj][r];
                float d = sqrtf(fmaxf(dist, 0.0f));
                d = fminf(fmaxf(d, 1e-8f), 1e8f);
                if (colok && (lab_s[row_l] != col_g)) sum += d;
            }
        }
    }

    #pragma unroll
    for (int off = 32; off; off >>= 1) sum += __shfl_down(sum, off);
    if (lane == 0) wsum[wid] = sum;
    __syncthreads();
    if (tid == 0) {
        float t = 0.0f;
        #pragma unroll
        for (int w = 0; w < 8; ++w) t += wsum[w];
        part[blockIdx.x] = t;
    }
}

// Reduce 256 partials -> loss. One block; no atomics anywhere.
__global__ void finalize(const float* __restrict__ part, float* __restrict__ out) {
    const int tid  = threadIdx.x;
    const int lane = tid & 63;
    const int wid  = tid >> 6;
    __shared__ float wsum[4];
    float s = part[tid];
    #pragma unroll
    for (int off = 32; off; off >>= 1) s += __shfl_down(s, off);
    if (lane == 0) wsum[wid] = s;
    __syncthreads();
    if (tid == 0)
        out[0] = (wsum[0] + wsum[1] + wsum[2] + wsum[3]) * (1.0f / (16384.0f * 999.0f));
}

extern "C" void kernel_launch(void* const* d_in, const int* in_sizes, int n_in,
                              void* d_out, int out_size, void* d_ws, size_t ws_size,
                              hipStream_t stream) {
    const float* x       = (const float*)d_in[0];
    const float* centers = (const float*)d_in[1];
    const int*   labels  = (const int*)d_in[2];
    float*       out     = (float*)d_out;

    char* ws = (char*)d_ws;
    char*  xq   = ws + WS_XQ;
    char*  cq   = ws + WS_CQ;
    float* xsq  = (float*)(ws + WS_XSQ);
    float* csq  = (float*)(ws + WS_CSQ);
    float* part = (float*)(ws + WS_PART);

    prep<<<272, 256, 0, stream>>>(x, centers, xq, cq, xsq, csq);
    gemm_loss<<<256, 512, 0, stream>>>(xq, cq, xsq, csq, labels, part);
    finalize<<<1, 256, 0, stream>>>(part, out);
}